// Round 3
// baseline (221.229 us; speedup 1.0000x reference)
//
#include <hip/hip_runtime.h>

#define N 1024
#define D 2048
#define P 8
#define F 9
#define KTOT (F * D)          // 18432
#define SPLIT 16
#define NSLOT 8               // z and z+8 share a partial slot via atomicAdd
#define KS (KTOT / SPLIT)     // 1152
#define BM 128                // tile M = N = 128
#define BKT 32                // K per step (16x16x32 MFMA)
#define MARGIN 0.3f

typedef float f32x4 __attribute__((ext_vector_type(4)));
typedef short s16x8 __attribute__((ext_vector_type(8)));

#define GLOBAL_AS __attribute__((address_space(1)))
#define LDS_AS __attribute__((address_space(3)))

__device__ __forceinline__ const float* feat_row(const float* __restrict__ g,
                                                 const float* __restrict__ p,
                                                 int i, int f) {
    return (f == 0) ? (g + (size_t)i * D)
                    : (p + ((size_t)i * P + (f - 1)) * D);
}

__device__ __forceinline__ unsigned f2bf(float x) {
    unsigned u = __float_as_uint(x);
    return (u + 0x7fffu + ((u >> 16) & 1u)) >> 16;   // RNE
}

// wave-per-row: norm + label-scale + bf16 convert, no barriers.
// V[(i*F+f)*D + k] = bf16( row[k] * label / (||row||+1e-12) )
__global__ __launch_bounds__(256)
void pack_kernel(const float* __restrict__ gfeat,
                 const float* __restrict__ pfeat,
                 const float* __restrict__ plab,
                 unsigned short* __restrict__ V) {
    const int wave = threadIdx.x >> 6, lane = threadIdx.x & 63;
    const int r = blockIdx.x * 4 + wave;          // 0..9215
    const int i = r / F, f = r % F;
    const float4* s4 = (const float4*)feat_row(gfeat, pfeat, i, f);
    float4 v[8];
    float ss = 0.f;
    #pragma unroll
    for (int q = 0; q < 8; ++q) {
        v[q] = s4[lane + 64 * q];
        ss += v[q].x*v[q].x + v[q].y*v[q].y + v[q].z*v[q].z + v[q].w*v[q].w;
    }
    #pragma unroll
    for (int m = 32; m >= 1; m >>= 1) ss += __shfl_xor(ss, m, 64);
    const float ls = (f == 0) ? 1.0f : plab[i * P + (f - 1)];
    const float inv = ls / (sqrtf(ss) + 1e-12f);
    #pragma unroll
    for (int q = 0; q < 8; ++q) {
        uint2 o;
        o.x = f2bf(v[q].x * inv) | (f2bf(v[q].y * inv) << 16);
        o.y = f2bf(v[q].z * inv) | (f2bf(v[q].w * inv) << 16);
        *(uint2*)&V[(size_t)r * D + (lane + 64 * q) * 4] = o;
    }
}

// C = V*V^T partials. 128x128 tile, SPLIT=16 (4 blocks/CU), XOR-swizzled LDS.
__global__ __launch_bounds__(256, 4)
void gemm_kernel(const unsigned short* __restrict__ V,
                 float* __restrict__ part) {
    // row-major [row][k] with 16B chunks XOR-swizzled: chunk c of row r lives
    // at slot (c ^ (r&3)). Staging stays coalesced; ds_read_b128 phases are
    // <=2-way bank conflicts (free).
    __shared__ short As[BM * BKT];   // 8 KB
    __shared__ short Bs[BM * BKT];   // 8 KB

    const int t = threadIdx.x;
    const int wave = t >> 6, lane = t & 63;
    const int i0 = blockIdx.y * BM;
    const int j0 = blockIdx.x * BM;
    const int kbase = blockIdx.z * KS;

    // staging: thread t fills slot t (and t+256): row t>>2, slot-chunk t&3,
    // which holds logical chunk (t&3)^((t>>2)&3)
    const int srow = t >> 2;
    const int schunk = (t & 3) ^ (srow & 3);
    const unsigned short* Ap = V + (size_t)(i0 + srow) * KTOT + kbase + schunk * 8;
    const unsigned short* Bp = V + (size_t)(j0 + srow) * KTOT + kbase + schunk * 8;

    // fragment bases: lane holds A[row = rA][k = kq*8..+7]
    const int kq = lane >> 4;
    const int rA = (wave & 1) * 64 + (lane & 15);
    const int rB = (wave >> 1) * 64 + (lane & 15);
    const short* Abase = As + rA * BKT + (kq ^ (rA & 3)) * 8;
    const short* Bbase = Bs + rB * BKT + (kq ^ (rB & 3)) * 8;

    f32x4 acc[4][4];
    #pragma unroll
    for (int m = 0; m < 4; ++m)
        #pragma unroll
        for (int n = 0; n < 4; ++n)
            acc[m][n] = (f32x4){0.f, 0.f, 0.f, 0.f};

    for (int ks = 0; ks < KS / BKT; ++ks) {
        __syncthreads();
        __builtin_amdgcn_global_load_lds((const GLOBAL_AS void*)Ap,
                                         (LDS_AS void*)(As + t * 8), 16, 0, 0);
        __builtin_amdgcn_global_load_lds((const GLOBAL_AS void*)(Ap + (size_t)64 * KTOT),
                                         (LDS_AS void*)(As + 2048 + t * 8), 16, 0, 0);
        __builtin_amdgcn_global_load_lds((const GLOBAL_AS void*)Bp,
                                         (LDS_AS void*)(Bs + t * 8), 16, 0, 0);
        __builtin_amdgcn_global_load_lds((const GLOBAL_AS void*)(Bp + (size_t)64 * KTOT),
                                         (LDS_AS void*)(Bs + 2048 + t * 8), 16, 0, 0);
        Ap += BKT;
        Bp += BKT;
        __syncthreads();

        s16x8 af[4], bf[4];
        #pragma unroll
        for (int m = 0; m < 4; ++m) af[m] = *(const s16x8*)(Abase + m * 16 * BKT);
        #pragma unroll
        for (int n = 0; n < 4; ++n) bf[n] = *(const s16x8*)(Bbase + n * 16 * BKT);
        #pragma unroll
        for (int m = 0; m < 4; ++m)
            #pragma unroll
            for (int n = 0; n < 4; ++n)
                acc[m][n] = __builtin_amdgcn_mfma_f32_16x16x32_bf16(
                    af[m], bf[n], acc[m][n], 0, 0, 0);
    }

    // C/D layout: col = lane&15, row = (lane>>4)*4 + reg
    float* outp = part + (size_t)(blockIdx.z & (NSLOT - 1)) * N * N;
    const int rbase = i0 + (wave & 1) * 64 + (lane >> 4) * 4;
    const int cbase = j0 + (wave >> 1) * 64 + (lane & 15);
    #pragma unroll
    for (int m = 0; m < 4; ++m)
        #pragma unroll
        for (int n = 0; n < 4; ++n)
            #pragma unroll
            for (int r = 0; r < 4; ++r)
                unsafeAtomicAdd(&outp[(size_t)(rbase + m * 16 + r) * N + cbase + n * 16],
                                acc[m][n][r]);
}

// fused: sum slot partials -> dist -> hardest pos/neg -> atomic mean
__global__ void mine_kernel(const float* __restrict__ part,
                            const float* __restrict__ plab,
                            const int* __restrict__ glab,
                            float* __restrict__ out) {
    const int i = blockIdx.x;
    const int t = threadIdx.x;
    const int li = glab[i];
    float lab_i[P];
    #pragma unroll
    for (int c = 0; c < P; ++c) lab_i[c] = plab[i * P + c];

    float ap = -1e30f, an = 1e30f;
    for (int j = t; j < N; j += 256) {
        float dot = 0.f;
        #pragma unroll
        for (int s = 0; s < NSLOT; ++s)
            dot += part[(size_t)s * N * N + (size_t)i * N + j];
        float ov = 0.f;
        #pragma unroll
        for (int c = 0; c < P; ++c) ov += lab_i[c] * plab[j * P + c];
        float d = 0.5f - dot / (2.0f * (ov + 1.0f));
        if (glab[j] == li) ap = fmaxf(ap, d);
        else               an = fminf(an, d);
    }
    __shared__ float smax[256], smin[256];
    smax[t] = ap; smin[t] = an;
    __syncthreads();
    for (int s = 128; s > 0; s >>= 1) {
        if (t < s) {
            smax[t] = fmaxf(smax[t], smax[t + s]);
            smin[t] = fminf(smin[t], smin[t + s]);
        }
        __syncthreads();
    }
    if (t == 0) {
        float loss = fmaxf(0.f, smax[0] - smin[0] + MARGIN);
        unsafeAtomicAdd(out, loss * (1.0f / N));
    }
}

extern "C" void kernel_launch(void* const* d_in, const int* in_sizes, int n_in,
                              void* d_out, int out_size, void* d_ws, size_t ws_size,
                              hipStream_t stream) {
    const float* gfeat = (const float*)d_in[0];
    const float* pfeat = (const float*)d_in[1];
    const float* plab  = (const float*)d_in[2];
    const int*   glab  = (const int*)d_in[3];
    float* out = (float*)d_out;

    char* ws = (char*)d_ws;
    unsigned short* V = (unsigned short*)ws;            // 37,748,736 B
    float* part = (float*)(ws + (size_t)37748736);      // 8*1024*1024*4 = 33,554,432 B
                                                        // total 71,303,168 B (== round-2 usage)

    hipMemsetAsync(part, 0, (size_t)NSLOT * N * N * sizeof(float), stream);
    hipMemsetAsync(out, 0, sizeof(float), stream);
    pack_kernel<<<(N * F) / 4, 256, 0, stream>>>(gfeat, pfeat, plab, V);
    gemm_kernel<<<dim3(N / BM, N / BM, SPLIT), 256, 0, stream>>>(V, part);
    mine_kernel<<<N, 256, 0, stream>>>(part, plab, glab, out);
}

// Round 4
// 204.411 us; speedup vs baseline: 1.0823x; 1.0823x over previous
//
#include <hip/hip_runtime.h>

#define N 1024
#define D 2048
#define P 8
#define F 9
#define KTOT (F * D)          // 18432
#define SPLIT 12
#define NSLOT 6               // slot = z % 6 -> 2 atomic contenders
#define KS (KTOT / SPLIT)     // 1536
#define BM 128
#define BKT 64                // K per staging iter (2 MFMA k-steps)
#define MARGIN 0.3f

typedef float f32x4 __attribute__((ext_vector_type(4)));
typedef short s16x8 __attribute__((ext_vector_type(8)));

#define GLOBAL_AS __attribute__((address_space(1)))
#define LDS_AS __attribute__((address_space(3)))

__device__ __forceinline__ const float* feat_row(const float* __restrict__ g,
                                                 const float* __restrict__ p,
                                                 int i, int f) {
    return (f == 0) ? (g + (size_t)i * D)
                    : (p + ((size_t)i * P + (f - 1)) * D);
}

__device__ __forceinline__ unsigned f2bf(float x) {
    unsigned u = __float_as_uint(x);
    return (u + 0x7fffu + ((u >> 16) & 1u)) >> 16;   // RNE
}

// wave-per-row: norm + label-scale + bf16 convert.
__global__ __launch_bounds__(256)
void pack_kernel(const float* __restrict__ gfeat,
                 const float* __restrict__ pfeat,
                 const float* __restrict__ plab,
                 unsigned short* __restrict__ V) {
    const int wave = threadIdx.x >> 6, lane = threadIdx.x & 63;
    const int r = blockIdx.x * 4 + wave;
    const int i = r / F, f = r % F;
    const float4* s4 = (const float4*)feat_row(gfeat, pfeat, i, f);
    float4 v[8];
    float ss = 0.f;
    #pragma unroll
    for (int q = 0; q < 8; ++q) {
        v[q] = s4[lane + 64 * q];
        ss += v[q].x*v[q].x + v[q].y*v[q].y + v[q].z*v[q].z + v[q].w*v[q].w;
    }
    #pragma unroll
    for (int m = 32; m >= 1; m >>= 1) ss += __shfl_xor(ss, m, 64);
    const float ls = (f == 0) ? 1.0f : plab[i * P + (f - 1)];
    const float inv = ls / (sqrtf(ss) + 1e-12f);
    #pragma unroll
    for (int q = 0; q < 8; ++q) {
        uint2 o;
        o.x = f2bf(v[q].x * inv) | (f2bf(v[q].y * inv) << 16);
        o.y = f2bf(v[q].z * inv) | (f2bf(v[q].w * inv) << 16);
        *(uint2*)&V[(size_t)r * D + (lane + 64 * q) * 4] = o;
    }
}

// C = V*V^T partials. 128x128 tile, BKT=64 (32 MFMA per barrier-pair),
// SPLIT=12 -> 768 blocks = 3/CU. LDS rows are 128 B (would be 16-way bank
// conflict); 16B chunks swizzled: slot = chunk ^ (row&7) -> <=2-way (free).
__global__ __launch_bounds__(256, 3)
void gemm_kernel(const unsigned short* __restrict__ V,
                 float* __restrict__ part) {
    __shared__ short As[BM * BKT];   // 16 KB
    __shared__ short Bs[BM * BKT];   // 16 KB

    const int t = threadIdx.x;
    const int wave = t >> 6, lane = t & 63;
    const int i0 = blockIdx.y * BM;
    const int j0 = blockIdx.x * BM;
    const int kbase = blockIdx.z * KS;

    // staging: phase p, thread t fills LDS slot (p*256+t) (16 B each):
    // row = 32p + (t>>3), slot_chunk = t&7, logical chunk = (t&7)^((t>>3)&7)
    // (row&7 == (t>>3)&7 since 32p = 0 mod 8). Source is coalesced 128 B/row.
    const int srow0 = t >> 3;                       // 0..31
    const int schunk = (t & 7) ^ (srow0 & 7);
    const unsigned short* Ap = V + (size_t)(i0 + srow0) * KTOT + kbase + schunk * 8;
    const unsigned short* Bp = V + (size_t)(j0 + srow0) * KTOT + kbase + schunk * 8;

    // fragment bases: lane reads row rA, k-step s covers chunks (s*4+kq)
    const int kq = lane >> 4;
    const int rA = (wave & 1) * 64 + (lane & 15);
    const int rB = (wave >> 1) * 64 + (lane & 15);
    const short* Ab0 = As + rA * BKT + ((kq    ) ^ (rA & 7)) * 8;
    const short* Ab1 = As + rA * BKT + ((4 + kq) ^ (rA & 7)) * 8;
    const short* Bb0 = Bs + rB * BKT + ((kq    ) ^ (rB & 7)) * 8;
    const short* Bb1 = Bs + rB * BKT + ((4 + kq) ^ (rB & 7)) * 8;

    f32x4 acc[4][4];
    #pragma unroll
    for (int m = 0; m < 4; ++m)
        #pragma unroll
        for (int n = 0; n < 4; ++n)
            acc[m][n] = (f32x4){0.f, 0.f, 0.f, 0.f};

    for (int ks = 0; ks < KS / BKT; ++ks) {
        __syncthreads();
        #pragma unroll
        for (int p = 0; p < 4; ++p) {
            __builtin_amdgcn_global_load_lds(
                (const GLOBAL_AS void*)(Ap + (size_t)(32 * p) * KTOT),
                (LDS_AS void*)(As + p * 2048 + t * 8), 16, 0, 0);
            __builtin_amdgcn_global_load_lds(
                (const GLOBAL_AS void*)(Bp + (size_t)(32 * p) * KTOT),
                (LDS_AS void*)(Bs + p * 2048 + t * 8), 16, 0, 0);
        }
        Ap += BKT;
        Bp += BKT;
        __syncthreads();

        {   // k-step 0
            s16x8 af[4], bf[4];
            #pragma unroll
            for (int m = 0; m < 4; ++m) af[m] = *(const s16x8*)(Ab0 + m * 16 * BKT);
            #pragma unroll
            for (int n = 0; n < 4; ++n) bf[n] = *(const s16x8*)(Bb0 + n * 16 * BKT);
            #pragma unroll
            for (int m = 0; m < 4; ++m)
                #pragma unroll
                for (int n = 0; n < 4; ++n)
                    acc[m][n] = __builtin_amdgcn_mfma_f32_16x16x32_bf16(
                        af[m], bf[n], acc[m][n], 0, 0, 0);
        }
        {   // k-step 1
            s16x8 af[4], bf[4];
            #pragma unroll
            for (int m = 0; m < 4; ++m) af[m] = *(const s16x8*)(Ab1 + m * 16 * BKT);
            #pragma unroll
            for (int n = 0; n < 4; ++n) bf[n] = *(const s16x8*)(Bb1 + n * 16 * BKT);
            #pragma unroll
            for (int m = 0; m < 4; ++m)
                #pragma unroll
                for (int n = 0; n < 4; ++n)
                    acc[m][n] = __builtin_amdgcn_mfma_f32_16x16x32_bf16(
                        af[m], bf[n], acc[m][n], 0, 0, 0);
        }
    }

    // C/D layout: col = lane&15, row = (lane>>4)*4 + reg
    float* outp = part + (size_t)(blockIdx.z % NSLOT) * N * N;
    const int rbase = i0 + (wave & 1) * 64 + (lane >> 4) * 4;
    const int cbase = j0 + (wave >> 1) * 64 + (lane & 15);
    #pragma unroll
    for (int m = 0; m < 4; ++m)
        #pragma unroll
        for (int n = 0; n < 4; ++n)
            #pragma unroll
            for (int r = 0; r < 4; ++r)
                unsafeAtomicAdd(&outp[(size_t)(rbase + m * 16 + r) * N + cbase + n * 16],
                                acc[m][n][r]);
}

// fused: sum slot partials -> dist -> hardest pos/neg -> atomic mean
__global__ void mine_kernel(const float* __restrict__ part,
                            const float* __restrict__ plab,
                            const int* __restrict__ glab,
                            float* __restrict__ out) {
    const int i = blockIdx.x;
    const int t = threadIdx.x;
    const int li = glab[i];
    float lab_i[P];
    #pragma unroll
    for (int c = 0; c < P; ++c) lab_i[c] = plab[i * P + c];

    float ap = -1e30f, an = 1e30f;
    for (int j = t; j < N; j += 256) {
        float dot = 0.f;
        #pragma unroll
        for (int s = 0; s < NSLOT; ++s)
            dot += part[(size_t)s * N * N + (size_t)i * N + j];
        float ov = 0.f;
        #pragma unroll
        for (int c = 0; c < P; ++c) ov += lab_i[c] * plab[j * P + c];
        float d = 0.5f - dot / (2.0f * (ov + 1.0f));
        if (glab[j] == li) ap = fmaxf(ap, d);
        else               an = fminf(an, d);
    }
    __shared__ float smax[256], smin[256];
    smax[t] = ap; smin[t] = an;
    __syncthreads();
    for (int s = 128; s > 0; s >>= 1) {
        if (t < s) {
            smax[t] = fmaxf(smax[t], smax[t + s]);
            smin[t] = fminf(smin[t], smin[t + s]);
        }
        __syncthreads();
    }
    if (t == 0) {
        float loss = fmaxf(0.f, smax[0] - smin[0] + MARGIN);
        unsafeAtomicAdd(out, loss * (1.0f / N));
    }
}

extern "C" void kernel_launch(void* const* d_in, const int* in_sizes, int n_in,
                              void* d_out, int out_size, void* d_ws, size_t ws_size,
                              hipStream_t stream) {
    const float* gfeat = (const float*)d_in[0];
    const float* pfeat = (const float*)d_in[1];
    const float* plab  = (const float*)d_in[2];
    const int*   glab  = (const int*)d_in[3];
    float* out = (float*)d_out;

    char* ws = (char*)d_ws;
    unsigned short* V = (unsigned short*)ws;            // 37,748,736 B
    float* part = (float*)(ws + (size_t)37748736);      // 6*1024*1024*4 = 25,165,824 B
                                                        // total 62,914,560 B

    hipMemsetAsync(part, 0, (size_t)NSLOT * N * N * sizeof(float), stream);
    hipMemsetAsync(out, 0, sizeof(float), stream);
    pack_kernel<<<(N * F) / 4, 256, 0, stream>>>(gfeat, pfeat, plab, V);
    gemm_kernel<<<dim3(N / BM, N / BM, SPLIT), 256, 0, stream>>>(V, part);
    mine_kernel<<<N, 256, 0, stream>>>(part, plab, glab, out);
}

// Round 5
// 203.175 us; speedup vs baseline: 1.0889x; 1.0061x over previous
//
#include <hip/hip_runtime.h>

#define N 1024
#define D 2048
#define P 8
#define F 9
#define KTOT (F * D)          // 18432
#define SPLIT 24
#define NSLOT 6               // slot = z % 6 -> 4 atomic contenders
#define KS (KTOT / SPLIT)     // 768
#define BM 128
#define BKT 32                // R2-proven inner geometry
#define NTILE 36              // upper-triangle 8x8 tile pairs (incl diag)
#define MARGIN 0.3f

typedef float f32x4 __attribute__((ext_vector_type(4)));
typedef short s16x8 __attribute__((ext_vector_type(8)));

#define GLOBAL_AS __attribute__((address_space(1)))
#define LDS_AS __attribute__((address_space(3)))

__device__ __forceinline__ const float* feat_row(const float* __restrict__ g,
                                                 const float* __restrict__ p,
                                                 int i, int f) {
    return (f == 0) ? (g + (size_t)i * D)
                    : (p + ((size_t)i * P + (f - 1)) * D);
}

__device__ __forceinline__ unsigned f2bf(float x) {
    unsigned u = __float_as_uint(x);
    return (u + 0x7fffu + ((u >> 16) & 1u)) >> 16;   // RNE
}

// map linear id 0..35 -> (bi, bj) with bi <= bj
__device__ __forceinline__ void tile_map(int lid, int& bi, int& bj) {
    int rem = lid, r = 0;
    while (rem >= 8 - r) { rem -= 8 - r; ++r; }
    bi = r;
    bj = r + rem;
}

// wave-per-row norm+scale+bf16 pack; also zeroes part and out (replaces memsets)
__global__ __launch_bounds__(256)
void pack_kernel(const float* __restrict__ gfeat,
                 const float* __restrict__ pfeat,
                 const float* __restrict__ plab,
                 unsigned short* __restrict__ V,
                 float* __restrict__ part,
                 float* __restrict__ out) {
    // zero the partial-accumulator slab (NSLOT*N*N floats) and the scalar out
    {
        float4 z4 = {0.f, 0.f, 0.f, 0.f};
        float4* p4 = (float4*)part;
        const size_t tot = (size_t)NSLOT * N * N / 4;
        for (size_t idx = (size_t)blockIdx.x * 256 + threadIdx.x; idx < tot;
             idx += (size_t)gridDim.x * 256)
            p4[idx] = z4;
        if (blockIdx.x == 0 && threadIdx.x == 0) out[0] = 0.f;
    }
    const int wave = threadIdx.x >> 6, lane = threadIdx.x & 63;
    const int r = blockIdx.x * 4 + wave;
    const int i = r / F, f = r % F;
    const float4* s4 = (const float4*)feat_row(gfeat, pfeat, i, f);
    float4 v[8];
    float ss = 0.f;
    #pragma unroll
    for (int q = 0; q < 8; ++q) {
        v[q] = s4[lane + 64 * q];
        ss += v[q].x*v[q].x + v[q].y*v[q].y + v[q].z*v[q].z + v[q].w*v[q].w;
    }
    #pragma unroll
    for (int m = 32; m >= 1; m >>= 1) ss += __shfl_xor(ss, m, 64);
    const float ls = (f == 0) ? 1.0f : plab[i * P + (f - 1)];
    const float inv = ls / (sqrtf(ss) + 1e-12f);
    #pragma unroll
    for (int q = 0; q < 8; ++q) {
        uint2 o;
        o.x = f2bf(v[q].x * inv) | (f2bf(v[q].y * inv) << 16);
        o.y = f2bf(v[q].z * inv) | (f2bf(v[q].w * inv) << 16);
        *(uint2*)&V[(size_t)r * D + (lane + 64 * q) * 4] = o;
    }
}

// Upper-triangle tiles only. blockIdx.x = tile lid (36), blockIdx.y = split z.
// R2-proven inner body: BKT=32, 16 MFMA/iter, no min-waves bound.
__global__ __launch_bounds__(256)
void gemm_kernel(const unsigned short* __restrict__ V,
                 float* __restrict__ part) {
    __shared__ short As[BM * BKT];   // 8 KB
    __shared__ short Bs[BM * BKT];   // 8 KB

    const int t = threadIdx.x;
    const int wave = t >> 6, lane = t & 63;
    int bi, bj;
    tile_map(blockIdx.x, bi, bj);
    const bool diag = (bi == bj);
    const int i0 = bi * BM;
    const int j0 = bj * BM;
    const int kbase = blockIdx.y * KS;

    const unsigned short* Ap = V + (size_t)(i0 + (t >> 2)) * KTOT + kbase + (t & 3) * 8;
    const unsigned short* Bp = V + (size_t)(j0 + (t >> 2)) * KTOT + kbase + (t & 3) * 8;

    const int kq = lane >> 4;
    const int rA = (wave & 1) * 64 + (lane & 15);
    const int rB = (wave >> 1) * 64 + (lane & 15);
    const short* Bsrc = diag ? As : Bs;        // diag tile: B fragments read A's LDS
    const short* Abase = As + rA * BKT + kq * 8;
    const short* Bbase = Bsrc + rB * BKT + kq * 8;

    f32x4 acc[4][4];
    #pragma unroll
    for (int m = 0; m < 4; ++m)
        #pragma unroll
        for (int n = 0; n < 4; ++n)
            acc[m][n] = (f32x4){0.f, 0.f, 0.f, 0.f};

    for (int ks = 0; ks < KS / BKT; ++ks) {
        __syncthreads();
        __builtin_amdgcn_global_load_lds((const GLOBAL_AS void*)Ap,
                                         (LDS_AS void*)(As + t * 8), 16, 0, 0);
        __builtin_amdgcn_global_load_lds((const GLOBAL_AS void*)(Ap + (size_t)64 * KTOT),
                                         (LDS_AS void*)(As + 2048 + t * 8), 16, 0, 0);
        if (!diag) {
            __builtin_amdgcn_global_load_lds((const GLOBAL_AS void*)Bp,
                                             (LDS_AS void*)(Bs + t * 8), 16, 0, 0);
            __builtin_amdgcn_global_load_lds((const GLOBAL_AS void*)(Bp + (size_t)64 * KTOT),
                                             (LDS_AS void*)(Bs + 2048 + t * 8), 16, 0, 0);
        }
        Ap += BKT;
        Bp += BKT;
        __syncthreads();

        s16x8 af[4], bf[4];
        #pragma unroll
        for (int m = 0; m < 4; ++m) af[m] = *(const s16x8*)(Abase + m * 16 * BKT);
        #pragma unroll
        for (int n = 0; n < 4; ++n) bf[n] = *(const s16x8*)(Bbase + n * 16 * BKT);
        #pragma unroll
        for (int m = 0; m < 4; ++m)
            #pragma unroll
            for (int n = 0; n < 4; ++n)
                acc[m][n] = __builtin_amdgcn_mfma_f32_16x16x32_bf16(
                    af[m], bf[n], acc[m][n], 0, 0, 0);
    }

    // C/D layout: col = lane&15, row = (lane>>4)*4 + reg
    float* outp = part + (size_t)(blockIdx.y % NSLOT) * N * N;
    const int rbase = i0 + (wave & 1) * 64 + (lane >> 4) * 4;
    const int cbase = j0 + (wave >> 1) * 64 + (lane & 15);
    #pragma unroll
    for (int m = 0; m < 4; ++m)
        #pragma unroll
        for (int n = 0; n < 4; ++n)
            #pragma unroll
            for (int r = 0; r < 4; ++r)
                unsafeAtomicAdd(&outp[(size_t)(rbase + m * 16 + r) * N + cbase + n * 16],
                                acc[m][n][r]);
}

// Sum slot partials -> dist epilogue -> write dist[i][j]; mirror dist[j][i]
// for off-diag tiles via padded-LDS transpose (plain stores, written once).
// grid: (8 row-chunks of 16, 36 tiles)
__global__ __launch_bounds__(256)
void finish_kernel(const float* __restrict__ part,
                   const float* __restrict__ plab,
                   float* __restrict__ dist) {
    __shared__ float T[128 * 36];    // stride 36 keeps float4 alignment, 18.4 KB
    const int q = blockIdx.x;        // 16-row chunk
    const int t = threadIdx.x;
    int bi, bj;
    tile_map(blockIdx.y, bi, bj);
    const bool diag = (bi == bj);

    #pragma unroll
    for (int k = 0; k < 2; ++k) {
        const int idx = k * 256 + t;           // 0..511 -> 16 rows x 32 col-groups
        const int r_l = idx >> 5;              // 0..15
        const int c4 = idx & 31;               // float4 col group
        const int i = bi * 128 + q * 16 + r_l;
        const int jb = bj * 128 + c4 * 4;
        float4 d = {0.f, 0.f, 0.f, 0.f};
        #pragma unroll
        for (int s = 0; s < NSLOT; ++s) {
            float4 p = *(const float4*)&part[(size_t)s * N * N + (size_t)i * N + jb];
            d.x += p.x; d.y += p.y; d.z += p.z; d.w += p.w;
        }
        float lab_i[P];
        #pragma unroll
        for (int c = 0; c < P; ++c) lab_i[c] = plab[i * P + c];
        float res[4];
        float dd[4] = {d.x, d.y, d.z, d.w};
        #pragma unroll
        for (int e = 0; e < 4; ++e) {
            float ov = 0.f;
            #pragma unroll
            for (int c = 0; c < P; ++c) ov += lab_i[c] * plab[(jb + e) * P + c];
            res[e] = 0.5f - dd[e] / (2.0f * (ov + 1.0f));
        }
        float4 o = {res[0], res[1], res[2], res[3]};
        *(float4*)&dist[(size_t)i * N + jb] = o;
        if (!diag) {
            #pragma unroll
            for (int e = 0; e < 4; ++e) T[(c4 * 4 + e) * 36 + r_l] = res[e];
        }
    }
    if (!diag) {
        __syncthreads();
        #pragma unroll
        for (int k = 0; k < 2; ++k) {
            const int idx = k * 256 + t;       // 0..511 -> 128 rows x 4 col-groups
            const int c_o = idx >> 2;          // 0..127 (mirrored row)
            const int r4 = idx & 3;            // float4 group within 16 cols
            float4 v = *(const float4*)&T[c_o * 36 + r4 * 4];
            *(float4*)&dist[(size_t)(bj * 128 + c_o) * N + bi * 128 + q * 16 + r4 * 4] = v;
        }
    }
}

// hardest pos/neg per row + atomic mean
__global__ __launch_bounds__(256)
void mine_kernel(const float* __restrict__ dist,
                 const int* __restrict__ glab,
                 float* __restrict__ out) {
    const int i = blockIdx.x;
    const int t = threadIdx.x;
    const int li = glab[i];
    float ap = -1e30f, an = 1e30f;
    for (int j = t; j < N; j += 256) {
        float d = dist[(size_t)i * N + j];
        if (glab[j] == li) ap = fmaxf(ap, d);
        else               an = fminf(an, d);
    }
    __shared__ float smax[256], smin[256];
    smax[t] = ap; smin[t] = an;
    __syncthreads();
    for (int s = 128; s > 0; s >>= 1) {
        if (t < s) {
            smax[t] = fmaxf(smax[t], smax[t + s]);
            smin[t] = fminf(smin[t], smin[t + s]);
        }
        __syncthreads();
    }
    if (t == 0) {
        float loss = fmaxf(0.f, smax[0] - smin[0] + MARGIN);
        unsafeAtomicAdd(out, loss * (1.0f / N));
    }
}

extern "C" void kernel_launch(void* const* d_in, const int* in_sizes, int n_in,
                              void* d_out, int out_size, void* d_ws, size_t ws_size,
                              hipStream_t stream) {
    const float* gfeat = (const float*)d_in[0];
    const float* pfeat = (const float*)d_in[1];
    const float* plab  = (const float*)d_in[2];
    const int*   glab  = (const int*)d_in[3];
    float* out = (float*)d_out;

    char* ws = (char*)d_ws;
    unsigned short* V = (unsigned short*)ws;                     // 37,748,736 B
    float* part = (float*)(ws + (size_t)37748736);               // 25,165,824 B
    float* dist = (float*)(ws + (size_t)37748736 + 25165824);    // 4,194,304 B
                                                                 // total 64 MiB

    pack_kernel<<<(N * F) / 4, 256, 0, stream>>>(gfeat, pfeat, plab, V, part, out);
    gemm_kernel<<<dim3(NTILE, SPLIT), 256, 0, stream>>>(V, part);
    finish_kernel<<<dim3(8, NTILE), 256, 0, stream>>>(part, plab, dist);
    mine_kernel<<<N, 256, 0, stream>>>(dist, glab, out);
}

// Round 6
// 200.693 us; speedup vs baseline: 1.1023x; 1.0124x over previous
//
#include <hip/hip_runtime.h>

#define N 1024
#define D 2048
#define P 8
#define F 9
#define KTOT (F * D)          // 18432
#define SPLIT 16
#define KS (KTOT / SPLIT)     // 1152
#define BM 128
#define BKT 32
#define NITER (KS / BKT)      // 36 (even -- required by the x2-unrolled pipeline)
#define NTILE 36              // upper-triangle tile pairs incl diag
#define MARGIN 0.3f

typedef float f32x4 __attribute__((ext_vector_type(4)));
typedef short s16x8 __attribute__((ext_vector_type(8)));

#define GLOBAL_AS __attribute__((address_space(1)))
#define LDS_AS __attribute__((address_space(3)))

__device__ __forceinline__ const float* feat_row(const float* __restrict__ g,
                                                 const float* __restrict__ p,
                                                 int i, int f) {
    return (f == 0) ? (g + (size_t)i * D)
                    : (p + ((size_t)i * P + (f - 1)) * D);
}

__device__ __forceinline__ unsigned f2bf(float x) {
    unsigned u = __float_as_uint(x);
    return (u + 0x7fffu + ((u >> 16) & 1u)) >> 16;   // RNE
}

// linear tile id 0..35 -> (bi, bj), bi <= bj
__device__ __forceinline__ void tile_map(int lid, int& bi, int& bj) {
    int rem = lid, r = 0;
    while (rem >= 8 - r) { rem -= 8 - r; ++r; }
    bi = r;
    bj = r + rem;
}

// wave-per-row norm+scale+bf16 pack; zeroes draw (2.36 MB) and out.
__global__ __launch_bounds__(256)
void pack_kernel(const float* __restrict__ gfeat,
                 const float* __restrict__ pfeat,
                 const float* __restrict__ plab,
                 unsigned short* __restrict__ V,
                 float* __restrict__ draw,
                 float* __restrict__ out) {
    {
        const int zi = blockIdx.x * 256 + threadIdx.x;
        if (zi < NTILE * BM * BM / 4)
            ((float4*)draw)[zi] = (float4){0.f, 0.f, 0.f, 0.f};
        if (zi == 0) out[0] = 0.f;
    }
    const int wave = threadIdx.x >> 6, lane = threadIdx.x & 63;
    const int r = blockIdx.x * 4 + wave;
    const int i = r / F, f = r % F;
    const float4* s4 = (const float4*)feat_row(gfeat, pfeat, i, f);
    float4 v[8];
    float ss = 0.f;
    #pragma unroll
    for (int q = 0; q < 8; ++q) {
        v[q] = s4[lane + 64 * q];
        ss += v[q].x*v[q].x + v[q].y*v[q].y + v[q].z*v[q].z + v[q].w*v[q].w;
    }
    #pragma unroll
    for (int m = 32; m >= 1; m >>= 1) ss += __shfl_xor(ss, m, 64);
    const float ls = (f == 0) ? 1.0f : plab[i * P + (f - 1)];
    const float inv = ls / (sqrtf(ss) + 1e-12f);
    #pragma unroll
    for (int q = 0; q < 8; ++q) {
        uint2 o;
        o.x = f2bf(v[q].x * inv) | (f2bf(v[q].y * inv) << 16);
        o.y = f2bf(v[q].z * inv) | (f2bf(v[q].w * inv) << 16);
        *(uint2*)&V[(size_t)r * D + (lane + 64 * q) * 4] = o;
    }
}

// Upper-triangle tiles, double-buffered LDS pipeline: prefetch for buffer
// 1-p is issued right after the barrier, so the vmcnt(0) drain at the NEXT
// barrier waits on a load that has aged one full compute phase.
__global__ __launch_bounds__(256)
void gemm_kernel(const unsigned short* __restrict__ V,
                 float* __restrict__ draw) {
    __shared__ short As[2][BM * BKT];   // 2 x 8 KB
    __shared__ short Bs[2][BM * BKT];   // 2 x 8 KB

    const int t = threadIdx.x;
    const int wave = t >> 6, lane = t & 63;
    int bi, bj;
    tile_map(blockIdx.x, bi, bj);
    const bool diag = (bi == bj);
    const int i0 = bi * BM;
    const int j0 = bj * BM;
    const int kbase = blockIdx.y * KS;

    const unsigned short* Ap = V + (size_t)(i0 + (t >> 2)) * KTOT + kbase + (t & 3) * 8;
    const unsigned short* Bp = V + (size_t)(j0 + (t >> 2)) * KTOT + kbase + (t & 3) * 8;

    const int kq = lane >> 4;
    const int rA = (wave & 1) * 64 + (lane & 15);
    const int rB = (wave >> 1) * 64 + (lane & 15);

    f32x4 acc[4][4];
    #pragma unroll
    for (int m = 0; m < 4; ++m)
        #pragma unroll
        for (int n = 0; n < 4; ++n)
            acc[m][n] = (f32x4){0.f, 0.f, 0.f, 0.f};

    auto stage = [&](int buf, int ks) {
        __builtin_amdgcn_global_load_lds(
            (const GLOBAL_AS void*)(Ap + ks * BKT),
            (LDS_AS void*)(As[buf] + t * 8), 16, 0, 0);
        __builtin_amdgcn_global_load_lds(
            (const GLOBAL_AS void*)(Ap + ks * BKT + (size_t)64 * KTOT),
            (LDS_AS void*)(As[buf] + 2048 + t * 8), 16, 0, 0);
        if (!diag) {
            __builtin_amdgcn_global_load_lds(
                (const GLOBAL_AS void*)(Bp + ks * BKT),
                (LDS_AS void*)(Bs[buf] + t * 8), 16, 0, 0);
            __builtin_amdgcn_global_load_lds(
                (const GLOBAL_AS void*)(Bp + ks * BKT + (size_t)64 * KTOT),
                (LDS_AS void*)(Bs[buf] + 2048 + t * 8), 16, 0, 0);
        }
    };

    auto compute = [&](int buf) {
        const short* Abase = As[buf] + rA * BKT + kq * 8;
        const short* Bbase = (diag ? As[buf] : Bs[buf]) + rB * BKT + kq * 8;
        s16x8 af[4], bfr[4];
        #pragma unroll
        for (int m = 0; m < 4; ++m) af[m] = *(const s16x8*)(Abase + m * 16 * BKT);
        #pragma unroll
        for (int n = 0; n < 4; ++n) bfr[n] = *(const s16x8*)(Bbase + n * 16 * BKT);
        #pragma unroll
        for (int m = 0; m < 4; ++m)
            #pragma unroll
            for (int n = 0; n < 4; ++n)
                acc[m][n] = __builtin_amdgcn_mfma_f32_16x16x32_bf16(
                    af[m], bfr[n], acc[m][n], 0, 0, 0);
    };

    stage(0, 0);
    for (int kk = 0; kk < NITER; kk += 2) {
        __syncthreads();                       // drains buf0's loads
        if (kk + 1 < NITER) stage(1, kk + 1);  // fly during buf0 compute
        compute(0);
        __syncthreads();                       // drains buf1's loads + buf0 readers
        if (kk + 2 < NITER) stage(0, kk + 2);
        compute(1);
    }

    // C/D layout: col = lane&15, row = (lane>>4)*4 + reg
    float* outp = draw + (size_t)blockIdx.x * BM * BM;
    const int rbase = (wave & 1) * 64 + (lane >> 4) * 4;
    const int cbase = (wave >> 1) * 64 + (lane & 15);
    #pragma unroll
    for (int m = 0; m < 4; ++m)
        #pragma unroll
        for (int n = 0; n < 4; ++n)
            #pragma unroll
            for (int r = 0; r < 4; ++r)
                unsafeAtomicAdd(&outp[(size_t)(rbase + m * 16 + r) * BM + cbase + n * 16],
                                acc[m][n][r]);
}

// fused finish+mine: read raw dot from symmetric tile storage, apply the
// overlap/dist epilogue on the fly, hardest pos/neg per row, atomic mean.
__global__ __launch_bounds__(256)
void mine_kernel(const float* __restrict__ draw,
                 const float* __restrict__ plab,
                 const int* __restrict__ glab,
                 float* __restrict__ out) {
    const int i = blockIdx.x;
    const int t = threadIdx.x;
    const int li = glab[i];
    const int bi = i >> 7, ri = i & 127;
    float lab_i[P];
    #pragma unroll
    for (int c = 0; c < P; ++c) lab_i[c] = plab[i * P + c];

    float ap = -1e30f, an = 1e30f;
    for (int j = t; j < N; j += 256) {
        const int bj = j >> 7, rj = j & 127;
        size_t idx;
        if (bi <= bj)
            idx = (size_t)(bi * (17 - bi) / 2 + (bj - bi)) * (BM * BM) + ri * BM + rj;
        else
            idx = (size_t)(bj * (17 - bj) / 2 + (bi - bj)) * (BM * BM) + rj * BM + ri;
        float raw = draw[idx];
        float ov = 0.f;
        #pragma unroll
        for (int c = 0; c < P; ++c) ov += lab_i[c] * plab[j * P + c];
        float d = 0.5f - raw / (2.0f * (ov + 1.0f));
        if (glab[j] == li) ap = fmaxf(ap, d);
        else               an = fminf(an, d);
    }
    __shared__ float smax[256], smin[256];
    smax[t] = ap; smin[t] = an;
    __syncthreads();
    for (int s = 128; s > 0; s >>= 1) {
        if (t < s) {
            smax[t] = fmaxf(smax[t], smax[t + s]);
            smin[t] = fminf(smin[t], smin[t + s]);
        }
        __syncthreads();
    }
    if (t == 0) {
        float loss = fmaxf(0.f, smax[0] - smin[0] + MARGIN);
        unsafeAtomicAdd(out, loss * (1.0f / N));
    }
}

extern "C" void kernel_launch(void* const* d_in, const int* in_sizes, int n_in,
                              void* d_out, int out_size, void* d_ws, size_t ws_size,
                              hipStream_t stream) {
    const float* gfeat = (const float*)d_in[0];
    const float* pfeat = (const float*)d_in[1];
    const float* plab  = (const float*)d_in[2];
    const int*   glab  = (const int*)d_in[3];
    float* out = (float*)d_out;

    char* ws = (char*)d_ws;
    unsigned short* V = (unsigned short*)ws;           // 37,748,736 B
    float* draw = (float*)(ws + (size_t)37748736);     // 36*128*128*4 = 2,359,296 B
                                                       // total 40,108,032 B (~40.1 MB)

    pack_kernel<<<(N * F) / 4, 256, 0, stream>>>(gfeat, pfeat, plab, V, draw, out);
    gemm_kernel<<<dim3(NTILE, SPLIT), 256, 0, stream>>>(V, draw);
    mine_kernel<<<N, 256, 0, stream>>>(draw, plab, glab, out);
}

// Round 7
// 187.361 us; speedup vs baseline: 1.1808x; 1.0712x over previous
//
#include <hip/hip_runtime.h>

#define N 1024
#define D 2048
#define P 8
#define F 9
#define KTOT (F * D)          // 18432
#define SPLIT 16
#define KS (KTOT / SPLIT)     // 1152
#define BM 128
#define BKT 64                // 128 B LDS rows; swizzle -> 0 bank conflicts (R4-proven)
#define NITER (KS / BKT)      // 18
#define NTILE 36              // upper-triangle tile pairs incl diag
#define MARGIN 0.3f

typedef float f32x4 __attribute__((ext_vector_type(4)));
typedef short s16x8 __attribute__((ext_vector_type(8)));

#define GLOBAL_AS __attribute__((address_space(1)))
#define LDS_AS __attribute__((address_space(3)))

__device__ __forceinline__ const float* feat_row(const float* __restrict__ g,
                                                 const float* __restrict__ p,
                                                 int i, int f) {
    return (f == 0) ? (g + (size_t)i * D)
                    : (p + ((size_t)i * P + (f - 1)) * D);
}

__device__ __forceinline__ unsigned f2bf(float x) {
    unsigned u = __float_as_uint(x);
    return (u + 0x7fffu + ((u >> 16) & 1u)) >> 16;   // RNE
}

// linear tile id 0..35 -> (bi, bj), bi <= bj
__device__ __forceinline__ void tile_map(int lid, int& bi, int& bj) {
    int rem = lid, r = 0;
    while (rem >= 8 - r) { rem -= 8 - r; ++r; }
    bi = r;
    bj = r + rem;
}

// wave-per-row norm+scale+bf16 pack; zeroes draw (2.36 MB) and out.
__global__ __launch_bounds__(256)
void pack_kernel(const float* __restrict__ gfeat,
                 const float* __restrict__ pfeat,
                 const float* __restrict__ plab,
                 unsigned short* __restrict__ V,
                 float* __restrict__ draw,
                 float* __restrict__ out) {
    {
        const int zi = blockIdx.x * 256 + threadIdx.x;
        if (zi < NTILE * BM * BM / 4)
            ((float4*)draw)[zi] = (float4){0.f, 0.f, 0.f, 0.f};
        if (zi == 0) out[0] = 0.f;
    }
    const int wave = threadIdx.x >> 6, lane = threadIdx.x & 63;
    const int r = blockIdx.x * 4 + wave;
    const int i = r / F, f = r % F;
    const float4* s4 = (const float4*)feat_row(gfeat, pfeat, i, f);
    float4 v[8];
    float ss = 0.f;
    #pragma unroll
    for (int q = 0; q < 8; ++q) {
        v[q] = s4[lane + 64 * q];
        ss += v[q].x*v[q].x + v[q].y*v[q].y + v[q].z*v[q].z + v[q].w*v[q].w;
    }
    #pragma unroll
    for (int m = 32; m >= 1; m >>= 1) ss += __shfl_xor(ss, m, 64);
    const float ls = (f == 0) ? 1.0f : plab[i * P + (f - 1)];
    const float inv = ls / (sqrtf(ss) + 1e-12f);
    #pragma unroll
    for (int q = 0; q < 8; ++q) {
        uint2 o;
        o.x = f2bf(v[q].x * inv) | (f2bf(v[q].y * inv) << 16);
        o.y = f2bf(v[q].z * inv) | (f2bf(v[q].w * inv) << 16);
        *(uint2*)&V[(size_t)r * D + (lane + 64 * q) * 4] = o;
    }
}

// Upper-triangle tiles. BKT=64, single-buffered, XOR-swizzled LDS
// (slot = chunk ^ (row&7), R4-proven 0 bank conflicts), NO min-waves bound
// (register-regime lesson from R3/R4: any bound serializes the MFMA body).
__global__ __launch_bounds__(256)
void gemm_kernel(const unsigned short* __restrict__ V,
                 float* __restrict__ draw) {
    __shared__ short As[BM * BKT];   // 16 KB
    __shared__ short Bs[BM * BKT];   // 16 KB

    const int t = threadIdx.x;
    const int wave = t >> 6, lane = t & 63;
    int bi, bj;
    tile_map(blockIdx.x, bi, bj);
    const bool diag = (bi == bj);
    const int i0 = bi * BM;
    const int j0 = bj * BM;
    const int kbase = blockIdx.y * KS;

    // staging: phase p (0..3), thread t -> LDS slot p*2048 + t*8 shorts.
    // row = 32p + (t>>3); slot_chunk = t&7 holds logical chunk (t&7)^((t>>3)&7).
    const int srow0 = t >> 3;                       // 0..31
    const int schunk = (t & 7) ^ (srow0 & 7);
    const unsigned short* Ap = V + (size_t)(i0 + srow0) * KTOT + kbase + schunk * 8;
    const unsigned short* Bp = V + (size_t)(j0 + srow0) * KTOT + kbase + schunk * 8;

    // fragment rows (swizzle-safe across m*16: 16 == 0 mod 8)
    const int kq = lane >> 4;
    const int rA = (wave & 1) * 64 + (lane & 15);
    const int rB = (wave >> 1) * 64 + (lane & 15);
    const short* Ab0 = As + rA * BKT + ((kq    ) ^ (rA & 7)) * 8;
    const short* Ab1 = As + rA * BKT + ((4 + kq) ^ (rA & 7)) * 8;
    const short* Bsrc = diag ? As : Bs;
    const short* Bb0 = Bsrc + rB * BKT + ((kq    ) ^ (rB & 7)) * 8;
    const short* Bb1 = Bsrc + rB * BKT + ((4 + kq) ^ (rB & 7)) * 8;

    f32x4 acc[4][4];
    #pragma unroll
    for (int m = 0; m < 4; ++m)
        #pragma unroll
        for (int n = 0; n < 4; ++n)
            acc[m][n] = (f32x4){0.f, 0.f, 0.f, 0.f};

    for (int ks = 0; ks < NITER; ++ks) {
        __syncthreads();
        #pragma unroll
        for (int p = 0; p < 4; ++p)
            __builtin_amdgcn_global_load_lds(
                (const GLOBAL_AS void*)(Ap + (size_t)(32 * p) * KTOT),
                (LDS_AS void*)(As + p * 2048 + t * 8), 16, 0, 0);
        if (!diag) {
            #pragma unroll
            for (int p = 0; p < 4; ++p)
                __builtin_amdgcn_global_load_lds(
                    (const GLOBAL_AS void*)(Bp + (size_t)(32 * p) * KTOT),
                    (LDS_AS void*)(Bs + p * 2048 + t * 8), 16, 0, 0);
        }
        Ap += BKT;
        Bp += BKT;
        __syncthreads();

        {   // k-step 0: all fragments first (register-parallel), then MFMAs
            s16x8 af[4], bfr[4];
            #pragma unroll
            for (int m = 0; m < 4; ++m) af[m] = *(const s16x8*)(Ab0 + m * 16 * BKT);
            #pragma unroll
            for (int n = 0; n < 4; ++n) bfr[n] = *(const s16x8*)(Bb0 + n * 16 * BKT);
            #pragma unroll
            for (int m = 0; m < 4; ++m)
                #pragma unroll
                for (int n = 0; n < 4; ++n)
                    acc[m][n] = __builtin_amdgcn_mfma_f32_16x16x32_bf16(
                        af[m], bfr[n], acc[m][n], 0, 0, 0);
        }
        {   // k-step 1
            s16x8 af[4], bfr[4];
            #pragma unroll
            for (int m = 0; m < 4; ++m) af[m] = *(const s16x8*)(Ab1 + m * 16 * BKT);
            #pragma unroll
            for (int n = 0; n < 4; ++n) bfr[n] = *(const s16x8*)(Bb1 + n * 16 * BKT);
            #pragma unroll
            for (int m = 0; m < 4; ++m)
                #pragma unroll
                for (int n = 0; n < 4; ++n)
                    acc[m][n] = __builtin_amdgcn_mfma_f32_16x16x32_bf16(
                        af[m], bfr[n], acc[m][n], 0, 0, 0);
        }
    }

    // C/D layout: col = lane&15, row = (lane>>4)*4 + reg
    float* outp = draw + (size_t)blockIdx.x * BM * BM;
    const int rbase = (wave & 1) * 64 + (lane >> 4) * 4;
    const int cbase = (wave >> 1) * 64 + (lane & 15);
    #pragma unroll
    for (int m = 0; m < 4; ++m)
        #pragma unroll
        for (int n = 0; n < 4; ++n)
            #pragma unroll
            for (int r = 0; r < 4; ++r)
                unsafeAtomicAdd(&outp[(size_t)(rbase + m * 16 + r) * BM + cbase + n * 16],
                                acc[m][n][r]);
}

// fused finish+mine: symmetric tile lookup -> dist epilogue -> hardest
// pos/neg per row -> atomic mean.
__global__ __launch_bounds__(256)
void mine_kernel(const float* __restrict__ draw,
                 const float* __restrict__ plab,
                 const int* __restrict__ glab,
                 float* __restrict__ out) {
    const int i = blockIdx.x;
    const int t = threadIdx.x;
    const int li = glab[i];
    const int bi = i >> 7, ri = i & 127;
    float lab_i[P];
    #pragma unroll
    for (int c = 0; c < P; ++c) lab_i[c] = plab[i * P + c];

    float ap = -1e30f, an = 1e30f;
    for (int j = t; j < N; j += 256) {
        const int bj = j >> 7, rj = j & 127;
        size_t idx;
        if (bi <= bj)
            idx = (size_t)(bi * (17 - bi) / 2 + (bj - bi)) * (BM * BM) + ri * BM + rj;
        else
            idx = (size_t)(bj * (17 - bj) / 2 + (bi - bj)) * (BM * BM) + rj * BM + ri;
        float raw = draw[idx];
        float ov = 0.f;
        #pragma unroll
        for (int c = 0; c < P; ++c) ov += lab_i[c] * plab[j * P + c];
        float d = 0.5f - raw / (2.0f * (ov + 1.0f));
        if (glab[j] == li) ap = fmaxf(ap, d);
        else               an = fminf(an, d);
    }
    __shared__ float smax[256], smin[256];
    smax[t] = ap; smin[t] = an;
    __syncthreads();
    for (int s = 128; s > 0; s >>= 1) {
        if (t < s) {
            smax[t] = fmaxf(smax[t], smax[t + s]);
            smin[t] = fminf(smin[t], smin[t + s]);
        }
        __syncthreads();
    }
    if (t == 0) {
        float loss = fmaxf(0.f, smax[0] - smin[0] + MARGIN);
        unsafeAtomicAdd(out, loss * (1.0f / N));
    }
}

extern "C" void kernel_launch(void* const* d_in, const int* in_sizes, int n_in,
                              void* d_out, int out_size, void* d_ws, size_t ws_size,
                              hipStream_t stream) {
    const float* gfeat = (const float*)d_in[0];
    const float* pfeat = (const float*)d_in[1];
    const float* plab  = (const float*)d_in[2];
    const int*   glab  = (const int*)d_in[3];
    float* out = (float*)d_out;

    char* ws = (char*)d_ws;
    unsigned short* V = (unsigned short*)ws;           // 37,748,736 B
    float* draw = (float*)(ws + (size_t)37748736);     // 2,359,296 B -> total ~40.1 MB

    pack_kernel<<<(N * F) / 4, 256, 0, stream>>>(gfeat, pfeat, plab, V, draw, out);
    gemm_kernel<<<dim3(NTILE, SPLIT), 256, 0, stream>>>(V, draw);
    mine_kernel<<<N, 256, 0, stream>>>(draw, plab, glab, out);
}